// Round 1
// baseline (3430.188 us; speedup 1.0000x reference)
//
#include <hip/hip_runtime.h>
#include <math.h>

// Problem constants (B=16, N=2048, C=512)
#define BB 16
#define NN 2048
#define CC 512
#define MM (BB * NN)   // 32768 flattened rows
#define TILE 64
#define KT 16

// ---------------------------------------------------------------------------
// Generic tiled fp32 GEMM  Y[M x Nc] = X[M x K] @ W[K x Nc]  with epilogues.
// mode 0: Y = acc + bias[c]
// mode 1: Y = (acc + bias[c]) * (col[r] / (1e-9 + col[r]))        (scaled v)
// mode 2: y = acc + bias; y = (y-mean)*rsqrt(var+1e-5)*g + b2;
//         Y = max(y,0) + xres[r,c]                                 (final)
// Block: 256 threads, 64x64 tile, 4x4 micro-tile per thread.
// ---------------------------------------------------------------------------
__global__ __launch_bounds__(256)
void gemm_ep(const float* __restrict__ X, const float* __restrict__ W,
             const float* __restrict__ bias,
             const float* __restrict__ colsum,
             const float* __restrict__ bn_scale, const float* __restrict__ bn_bias,
             const float* __restrict__ bn_mean, const float* __restrict__ bn_var,
             const float* __restrict__ xres,
             float* __restrict__ Y,
             int K, int Nc, int mode)
{
    __shared__ float As[KT][TILE];   // As[k][m]
    __shared__ float Bs[KT][TILE];   // Bs[k][n]

    const int t  = threadIdx.x;
    const int tc = t & 15;          // 0..15  -> cols tc*4..tc*4+3
    const int tr = t >> 4;          // 0..15  -> rows tr*4..tr*4+3
    const int m0 = blockIdx.x * TILE;
    const int n0 = blockIdx.y * TILE;

    // staging indices
    const int lm  = t >> 2;         // 0..63 row within X tile
    const int lk4 = (t & 3) << 2;   // k offset (float4)
    const int lkB = t >> 4;         // 0..15 k row within W tile
    const int lnB = (t & 15) << 2;  // col offset (float4)

    float acc[4][4] = {};

    for (int kt = 0; kt < K; kt += KT) {
        const float4 xa = *(const float4*)(X + (size_t)(m0 + lm) * K + kt + lk4);
        As[lk4 + 0][lm] = xa.x;
        As[lk4 + 1][lm] = xa.y;
        As[lk4 + 2][lm] = xa.z;
        As[lk4 + 3][lm] = xa.w;
        *(float4*)&Bs[lkB][lnB] =
            *(const float4*)(W + (size_t)(kt + lkB) * Nc + n0 + lnB);
        __syncthreads();
#pragma unroll
        for (int k = 0; k < KT; ++k) {
            float av[4], bv[4];
            *(float4*)av = *(const float4*)&As[k][tr * 4];
            *(float4*)bv = *(const float4*)&Bs[k][tc * 4];
#pragma unroll
            for (int i = 0; i < 4; ++i)
#pragma unroll
                for (int j = 0; j < 4; ++j)
                    acc[i][j] = fmaf(av[i], bv[j], acc[i][j]);
        }
        __syncthreads();
    }

#pragma unroll
    for (int i = 0; i < 4; ++i) {
        const int row = m0 + tr * 4 + i;
#pragma unroll
        for (int j = 0; j < 4; ++j) {
            const int ccol = n0 + tc * 4 + j;
            float y = acc[i][j] + bias[ccol];
            if (mode == 1) {
                const float cs = colsum[row];
                y *= cs / (1e-9f + cs);
            } else if (mode == 2) {
                y = (y - bn_mean[ccol]) * rsqrtf(bn_var[ccol] + 1e-5f)
                        * bn_scale[ccol] + bn_bias[ccol];
                y = fmaxf(y, 0.0f) + xres[(size_t)row * Nc + ccol];
            }
            Y[(size_t)row * Nc + ccol] = y;
        }
    }
}

// ---------------------------------------------------------------------------
// Pass A: per-row online softmax stats of S = q @ k^T (per batch).
// Block: (row-tile of 64, batch). Streams all 32 n-tiles.
// ---------------------------------------------------------------------------
__global__ __launch_bounds__(256)
void attn_rowstats(const float* __restrict__ q, const float* __restrict__ kk,
                   float* __restrict__ rmax, float* __restrict__ rsum)
{
    __shared__ float Qs[KT][TILE];
    __shared__ float Ks[KT][TILE];
    __shared__ float red[TILE][17];   // +1 pad: avoid 4-way bank conflict
    __shared__ float mrun[TILE], lrun[TILE], mnew_s[TILE], mold_s[TILE];

    const int b  = blockIdx.y;
    const int m0 = blockIdx.x * TILE;
    const float* qb = q  + (size_t)b * NN * CC;
    const float* kb = kk + (size_t)b * NN * CC;

    const int t  = threadIdx.x;
    const int tc = t & 15;
    const int tr = t >> 4;
    const int lm  = t >> 2;
    const int lk4 = (t & 3) << 2;

    if (t < TILE) { mrun[t] = -3.0e38f; lrun[t] = 0.0f; }
    __syncthreads();

    for (int n0 = 0; n0 < NN; n0 += TILE) {
        float acc[4][4] = {};
        for (int kt = 0; kt < CC; kt += KT) {
            const float4 xa = *(const float4*)(qb + (size_t)(m0 + lm) * CC + kt + lk4);
            Qs[lk4 + 0][lm] = xa.x; Qs[lk4 + 1][lm] = xa.y;
            Qs[lk4 + 2][lm] = xa.z; Qs[lk4 + 3][lm] = xa.w;
            const float4 xb = *(const float4*)(kb + (size_t)(n0 + lm) * CC + kt + lk4);
            Ks[lk4 + 0][lm] = xb.x; Ks[lk4 + 1][lm] = xb.y;
            Ks[lk4 + 2][lm] = xb.z; Ks[lk4 + 3][lm] = xb.w;
            __syncthreads();
#pragma unroll
            for (int k = 0; k < KT; ++k) {
                float av[4], bv[4];
                *(float4*)av = *(const float4*)&Qs[k][tr * 4];
                *(float4*)bv = *(const float4*)&Ks[k][tc * 4];
#pragma unroll
                for (int i = 0; i < 4; ++i)
#pragma unroll
                    for (int j = 0; j < 4; ++j)
                        acc[i][j] = fmaf(av[i], bv[j], acc[i][j]);
            }
            __syncthreads();
        }
        // per-thread row maxima (4 rows x 4 cols)
#pragma unroll
        for (int i = 0; i < 4; ++i) {
            const float mx = fmaxf(fmaxf(acc[i][0], acc[i][1]),
                                   fmaxf(acc[i][2], acc[i][3]));
            red[tr * 4 + i][tc] = mx;
        }
        __syncthreads();
        if (t < TILE) {
            float mx = red[t][0];
#pragma unroll
            for (int j = 1; j < 16; ++j) mx = fmaxf(mx, red[t][j]);
            const float mo = mrun[t];
            const float mn = fmaxf(mo, mx);
            mold_s[t] = mo; mnew_s[t] = mn; mrun[t] = mn;
        }
        __syncthreads();
#pragma unroll
        for (int i = 0; i < 4; ++i) {
            const float mn = mnew_s[tr * 4 + i];
            const float s = __expf(acc[i][0] - mn) + __expf(acc[i][1] - mn)
                          + __expf(acc[i][2] - mn) + __expf(acc[i][3] - mn);
            red[tr * 4 + i][tc] = s;
        }
        __syncthreads();
        if (t < TILE) {
            float s = 0.0f;
#pragma unroll
            for (int j = 0; j < 16; ++j) s += red[t][j];
            lrun[t] = lrun[t] * __expf(mold_s[t] - mnew_s[t]) + s;
        }
        __syncthreads();
    }
    if (t < TILE) {
        rmax[(size_t)b * NN + m0 + t] = mrun[t];
        rsum[(size_t)b * NN + m0 + t] = lrun[t];
    }
}

// ---------------------------------------------------------------------------
// Pass B: column sums of normalized attention:
//   col[n] = sum_m exp(S[m,n] - rmax[m]) / rsum[m]
// Block: (col-tile of 64, batch). Streams all 32 m-tiles; register accum.
// ---------------------------------------------------------------------------
__global__ __launch_bounds__(256)
void attn_colsum(const float* __restrict__ q, const float* __restrict__ kk,
                 const float* __restrict__ rmax, const float* __restrict__ rsum,
                 float* __restrict__ colsum)
{
    __shared__ float Qs[KT][TILE];
    __shared__ float Ks[KT][TILE];
    __shared__ float red[TILE][17];
    __shared__ float rm_s[TILE], rs_s[TILE];

    const int b  = blockIdx.y;
    const int n0 = blockIdx.x * TILE;   // column tile
    const float* qb = q  + (size_t)b * NN * CC;
    const float* kb = kk + (size_t)b * NN * CC;

    const int t  = threadIdx.x;
    const int tc = t & 15;
    const int tr = t >> 4;
    const int lm  = t >> 2;
    const int lk4 = (t & 3) << 2;

    float csum[4] = {0.0f, 0.0f, 0.0f, 0.0f};

    for (int m0 = 0; m0 < NN; m0 += TILE) {
        if (t < TILE) {
            rm_s[t] = rmax[(size_t)b * NN + m0 + t];
            rs_s[t] = rsum[(size_t)b * NN + m0 + t];
        }
        float acc[4][4] = {};
        for (int kt = 0; kt < CC; kt += KT) {
            const float4 xa = *(const float4*)(qb + (size_t)(m0 + lm) * CC + kt + lk4);
            Qs[lk4 + 0][lm] = xa.x; Qs[lk4 + 1][lm] = xa.y;
            Qs[lk4 + 2][lm] = xa.z; Qs[lk4 + 3][lm] = xa.w;
            const float4 xb = *(const float4*)(kb + (size_t)(n0 + lm) * CC + kt + lk4);
            Ks[lk4 + 0][lm] = xb.x; Ks[lk4 + 1][lm] = xb.y;
            Ks[lk4 + 2][lm] = xb.z; Ks[lk4 + 3][lm] = xb.w;
            __syncthreads();
#pragma unroll
            for (int k = 0; k < KT; ++k) {
                float av[4], bv[4];
                *(float4*)av = *(const float4*)&Qs[k][tr * 4];
                *(float4*)bv = *(const float4*)&Ks[k][tc * 4];
#pragma unroll
                for (int i = 0; i < 4; ++i)
#pragma unroll
                    for (int j = 0; j < 4; ++j)
                        acc[i][j] = fmaf(av[i], bv[j], acc[i][j]);
            }
            __syncthreads();
        }
        // accumulate p = exp(s - rmax)/rsum into per-thread column sums
#pragma unroll
        for (int i = 0; i < 4; ++i) {
            const int rrow = tr * 4 + i;     // row index within m-tile
            const float mr  = rm_s[rrow];
            const float inv = 1.0f / rs_s[rrow];
#pragma unroll
            for (int j = 0; j < 4; ++j)
                csum[j] += __expf(acc[i][j] - mr) * inv;
        }
        __syncthreads();   // protect rm_s/rs_s before next tile's reload
    }

    // reduce csum over the 16 tr-groups
#pragma unroll
    for (int j = 0; j < 4; ++j) red[tc * 4 + j][tr] = csum[j];
    __syncthreads();
    if (t < TILE) {
        float s = 0.0f;
#pragma unroll
        for (int j = 0; j < 16; ++j) s += red[t][j];
        colsum[(size_t)b * NN + n0 + t] = s;
    }
}

// ---------------------------------------------------------------------------
// Launch: q,k GEMMs -> row stats -> col sums -> scaled-v GEMM -> final GEMM.
// Workspace layout (fp32): q[M*C] | k[M*C] | rmax[M] | rsum[M] | col[M]
// = 2*16.78M + 3*32768 floats ~= 128.4 MiB.  t reuses q's buffer.
// ---------------------------------------------------------------------------
extern "C" void kernel_launch(void* const* d_in, const int* in_sizes, int n_in,
                              void* d_out, int out_size, void* d_ws, size_t ws_size,
                              hipStream_t stream)
{
    const float* x        = (const float*)d_in[0];
    const float* Wq       = (const float*)d_in[1];
    const float* bq       = (const float*)d_in[2];
    const float* Wk       = (const float*)d_in[3];
    const float* bk       = (const float*)d_in[4];
    const float* Wv       = (const float*)d_in[5];
    const float* bv       = (const float*)d_in[6];
    const float* Wo       = (const float*)d_in[7];
    const float* bo       = (const float*)d_in[8];
    const float* bn_scale = (const float*)d_in[9];
    const float* bn_bias  = (const float*)d_in[10];
    const float* bn_mean  = (const float*)d_in[11];
    const float* bn_var   = (const float*)d_in[12];
    float* out = (float*)d_out;

    float* ws   = (float*)d_ws;
    float* q    = ws;
    float* kbuf = ws + (size_t)MM * CC;
    float* rmax = ws + 2 * (size_t)MM * CC;
    float* rsum = rmax + MM;
    float* col  = rsum + MM;
    float* tbuf = q;   // q is dead after attn passes; reuse for scaled-v

    const dim3 blk(256);
    const dim3 gproj(MM / TILE, CC / TILE);   // 512 x 8
    const dim3 gattn(NN / TILE, BB);          // 32 x 16

    // q = x@Wq + bq ; k = x@Wk + bk
    gemm_ep<<<gproj, blk, 0, stream>>>(x, Wq, bq, nullptr, nullptr, nullptr,
                                       nullptr, nullptr, nullptr, q, CC, CC, 0);
    gemm_ep<<<gproj, blk, 0, stream>>>(x, Wk, bk, nullptr, nullptr, nullptr,
                                       nullptr, nullptr, nullptr, kbuf, CC, CC, 0);
    // softmax row stats, then column sums
    attn_rowstats<<<gattn, blk, 0, stream>>>(q, kbuf, rmax, rsum);
    attn_colsum<<<gattn, blk, 0, stream>>>(q, kbuf, rmax, rsum, col);
    // t = (col/(eps+col)) * (x@Wv + bv)
    gemm_ep<<<gproj, blk, 0, stream>>>(x, Wv, bv, col, nullptr, nullptr,
                                       nullptr, nullptr, nullptr, tbuf, CC, CC, 1);
    // out = relu(BN(t@Wo + bo)) + x
    gemm_ep<<<gproj, blk, 0, stream>>>(tbuf, Wo, bo, nullptr, bn_scale, bn_bias,
                                       bn_mean, bn_var, x, out, CC, CC, 2);
}

// Round 2
// 1711.210 us; speedup vs baseline: 2.0045x; 2.0045x over previous
//
#include <hip/hip_runtime.h>
#include <math.h>

// Problem constants (B=16, N=2048, C=512)
#define BB 16
#define NN 2048
#define CC 512
#define MM (BB * NN)   // 32768 flattened rows
#define TILE 64
#define KT 16

typedef _Float16 half8 __attribute__((ext_vector_type(8)));
typedef _Float16 half4 __attribute__((ext_vector_type(4)));
typedef float floatx4 __attribute__((ext_vector_type(4)));

// async global->LDS, 16B per lane; LDS dest = wave-uniform base + lane*16
#define GLD16(gp, lp) __builtin_amdgcn_global_load_lds( \
    (const __attribute__((address_space(1))) void*)(gp), \
    (__attribute__((address_space(3))) void*)(lp), 16, 0, 0)

// ---------------------------------------------------------------------------
// fp32 tiled GEMM  Y[M x Nc] = X[M x K] @ W[K x Nc]  with epilogues.
// mode 1: Y = (acc + bias[c]) * colsc[r]                      (scaled v)
// mode 2: y = acc + bias; y = BN(y); Y = relu(y) + xres       (final)
// mode 3: split-store: outh = f16(y), outl = f16(y - outh)    (q/k proj)
// ---------------------------------------------------------------------------
__global__ __launch_bounds__(256)
void gemm_ep(const float* __restrict__ X, const float* __restrict__ W,
             const float* __restrict__ bias,
             const float* __restrict__ colsc,
             const float* __restrict__ bn_scale, const float* __restrict__ bn_bias,
             const float* __restrict__ bn_mean, const float* __restrict__ bn_var,
             const float* __restrict__ xres,
             float* __restrict__ Y,
             _Float16* __restrict__ outh, _Float16* __restrict__ outl,
             int K, int Nc, int mode)
{
    __shared__ float As[KT][TILE];
    __shared__ float Bs[KT][TILE];

    const int t  = threadIdx.x;
    const int tc = t & 15;
    const int tr = t >> 4;
    const int m0 = blockIdx.x * TILE;
    const int n0 = blockIdx.y * TILE;

    const int lm  = t >> 2;
    const int lk4 = (t & 3) << 2;
    const int lkB = t >> 4;
    const int lnB = (t & 15) << 2;

    float acc[4][4] = {};

    for (int kt = 0; kt < K; kt += KT) {
        const float4 xa = *(const float4*)(X + (size_t)(m0 + lm) * K + kt + lk4);
        As[lk4 + 0][lm] = xa.x;
        As[lk4 + 1][lm] = xa.y;
        As[lk4 + 2][lm] = xa.z;
        As[lk4 + 3][lm] = xa.w;
        *(float4*)&Bs[lkB][lnB] =
            *(const float4*)(W + (size_t)(kt + lkB) * Nc + n0 + lnB);
        __syncthreads();
#pragma unroll
        for (int k = 0; k < KT; ++k) {
            float av[4], bv[4];
            *(float4*)av = *(const float4*)&As[k][tr * 4];
            *(float4*)bv = *(const float4*)&Bs[k][tc * 4];
#pragma unroll
            for (int i = 0; i < 4; ++i)
#pragma unroll
                for (int j = 0; j < 4; ++j)
                    acc[i][j] = fmaf(av[i], bv[j], acc[i][j]);
        }
        __syncthreads();
    }

#pragma unroll
    for (int i = 0; i < 4; ++i) {
        const int row = m0 + tr * 4 + i;
        if (mode == 3) {
            half4 hv, lv;
#pragma unroll
            for (int j = 0; j < 4; ++j) {
                const float y = acc[i][j] + bias[n0 + tc * 4 + j];
                const _Float16 h = (_Float16)y;
                hv[j] = h;
                lv[j] = (_Float16)(y - (float)h);
            }
            *(half4*)(outh + (size_t)row * Nc + n0 + tc * 4) = hv;
            *(half4*)(outl + (size_t)row * Nc + n0 + tc * 4) = lv;
        } else {
#pragma unroll
            for (int j = 0; j < 4; ++j) {
                const int ccol = n0 + tc * 4 + j;
                float y = acc[i][j] + bias[ccol];
                if (mode == 1) {
                    y *= colsc[row];
                } else {
                    y = (y - bn_mean[ccol]) * rsqrtf(bn_var[ccol] + 1e-5f)
                            * bn_scale[ccol] + bn_bias[ccol];
                    y = fmaxf(y, 0.0f) + xres[(size_t)row * Nc + ccol];
                }
                Y[(size_t)row * Nc + ccol] = y;
            }
        }
    }
}

// ---------------------------------------------------------------------------
// Pass A (MFMA): per-row online softmax stats of S = q @ k^T; emits
// rho[m] = rowmax[m] + log(rowsumexp[m]).
// Block: 256 thr / 4 waves; 64 q-rows per block; n-chunks of 128.
// Wave w computes cols [w*32, w*32+32) of each chunk (4 row-tiles x 2 col-tiles).
// Split-f16: S = qh*kh + qh*kl + ql*kh (fp32-quality logits).
// ---------------------------------------------------------------------------
__global__ __launch_bounds__(256)
void attn_rowstats(const _Float16* __restrict__ qh, const _Float16* __restrict__ ql,
                   const _Float16* __restrict__ kh, const _Float16* __restrict__ kl,
                   float* __restrict__ rho)
{
    __shared__ __align__(16) _Float16 sQh[64 * 32], sQl[64 * 32];
    __shared__ __align__(16) _Float16 sKh[128 * 32], sKl[128 * 32];
    __shared__ float wred[4][64];
    __shared__ float mrun[64], lrun[64], mnew[64], coef[64];

    const int b  = blockIdx.y;
    const int m0 = blockIdx.x * 64;
    const int t = threadIdx.x, lane = t & 63, w = t >> 6;
    const size_t baseq = ((size_t)b * NN + m0) * CC;
    const size_t basek = (size_t)b * NN * CC;

    const int lr4 = lane >> 2;        // 0..15 row within 16-row staging group
    const int lc8 = (lane & 3) * 8;   // half offset within 32-half row
    const int fr  = lane & 15;        // fragment row/col
    const int fk  = (lane >> 4) * 8;  // fragment k offset (halves)
    const int g4  = lane >> 4;        // 0..3

    if (t < 64) { mrun[t] = -3.0e38f; lrun[t] = 0.0f; }
    __syncthreads();

    for (int n0 = 0; n0 < NN; n0 += 128) {
        floatx4 acc[4][2];
#pragma unroll
        for (int i = 0; i < 4; ++i)
#pragma unroll
            for (int j = 0; j < 2; ++j) acc[i][j] = (floatx4){0.f, 0.f, 0.f, 0.f};

        for (int kt = 0; kt < CC; kt += 32) {
            // stage Q 64x32 (wave w: rows w*16..w*16+15), hi & lo
            {
                const size_t go = baseq + (size_t)(w * 16 + lr4) * CC + kt + lc8;
                GLD16(qh + go, sQh + (w * 16) * 32);
                GLD16(ql + go, sQl + (w * 16) * 32);
            }
            // stage K 128x32 (wave w: rows w*32..w*32+31), hi & lo
#pragma unroll
            for (int c = 0; c < 2; ++c) {
                const int r = w * 32 + c * 16 + lr4;
                const size_t go = basek + (size_t)(n0 + r) * CC + kt + lc8;
                GLD16(kh + go, sKh + (w * 32 + c * 16) * 32);
                GLD16(kl + go, sKl + (w * 32 + c * 16) * 32);
            }
            __syncthreads();

            half8 ah[4], al[4], bh[2], bl[2];
#pragma unroll
            for (int rt = 0; rt < 4; ++rt) {
                ah[rt] = *(const half8*)&sQh[(rt * 16 + fr) * 32 + fk];
                al[rt] = *(const half8*)&sQl[(rt * 16 + fr) * 32 + fk];
            }
#pragma unroll
            for (int ct = 0; ct < 2; ++ct) {
                bh[ct] = *(const half8*)&sKh[(w * 32 + ct * 16 + fr) * 32 + fk];
                bl[ct] = *(const half8*)&sKl[(w * 32 + ct * 16 + fr) * 32 + fk];
            }
#pragma unroll
            for (int rt = 0; rt < 4; ++rt)
#pragma unroll
                for (int ct = 0; ct < 2; ++ct) {
                    acc[rt][ct] = __builtin_amdgcn_mfma_f32_16x16x32_f16(
                        ah[rt], bh[ct], acc[rt][ct], 0, 0, 0);
                    acc[rt][ct] = __builtin_amdgcn_mfma_f32_16x16x32_f16(
                        ah[rt], bl[ct], acc[rt][ct], 0, 0, 0);
                    acc[rt][ct] = __builtin_amdgcn_mfma_f32_16x16x32_f16(
                        al[rt], bh[ct], acc[rt][ct], 0, 0, 0);
                }
            __syncthreads();
        }

        // ---- chunk row-max (over this wave's 32 cols, then across waves) ----
#pragma unroll
        for (int rt = 0; rt < 4; ++rt)
#pragma unroll
            for (int reg = 0; reg < 4; ++reg) {
                float mx = fmaxf(acc[rt][0][reg], acc[rt][1][reg]);
                mx = fmaxf(mx, __shfl_xor(mx, 1));
                mx = fmaxf(mx, __shfl_xor(mx, 2));
                mx = fmaxf(mx, __shfl_xor(mx, 4));
                mx = fmaxf(mx, __shfl_xor(mx, 8));
                if ((lane & 15) == 0) wred[w][rt * 16 + g4 * 4 + reg] = mx;
            }
        __syncthreads();
        if (t < 64) {
            const float cm = fmaxf(fmaxf(wred[0][t], wred[1][t]),
                                   fmaxf(wred[2][t], wred[3][t]));
            const float mo = mrun[t];
            const float mn = fmaxf(mo, cm);
            mnew[t] = mn; coef[t] = __expf(mo - mn); mrun[t] = mn;
        }
        __syncthreads();
        // ---- chunk row-sum of exp ----
#pragma unroll
        for (int rt = 0; rt < 4; ++rt)
#pragma unroll
            for (int reg = 0; reg < 4; ++reg) {
                const int row = rt * 16 + g4 * 4 + reg;
                const float mn = mnew[row];
                float e = __expf(acc[rt][0][reg] - mn)
                        + __expf(acc[rt][1][reg] - mn);
                e += __shfl_xor(e, 1);
                e += __shfl_xor(e, 2);
                e += __shfl_xor(e, 4);
                e += __shfl_xor(e, 8);
                if ((lane & 15) == 0) wred[w][row] = e;
            }
        __syncthreads();
        if (t < 64)
            lrun[t] = lrun[t] * coef[t]
                    + (wred[0][t] + wred[1][t] + wred[2][t] + wred[3][t]);
        __syncthreads();
    }
    if (t < 64)
        rho[(size_t)b * NN + m0 + t] = mrun[t] + __logf(lrun[t]);
}

// ---------------------------------------------------------------------------
// Pass B (MFMA): colsc[n] = c/(eps+c), c = sum_m exp(S[m,n] - rho[m]).
// Block: 64 cols; m-chunks of 128. Wave w computes rows [w*32, w*32+32),
// all 64 cols (2 row-tiles x 4 col-tiles). Register column accumulators.
// ---------------------------------------------------------------------------
__global__ __launch_bounds__(256)
void attn_colsum(const _Float16* __restrict__ qh, const _Float16* __restrict__ ql,
                 const _Float16* __restrict__ kh, const _Float16* __restrict__ kl,
                 const float* __restrict__ rho, float* __restrict__ colsc)
{
    __shared__ __align__(16) _Float16 sQh[128 * 32], sQl[128 * 32];
    __shared__ __align__(16) _Float16 sKh[64 * 32], sKl[64 * 32];
    __shared__ float rho_s[128];
    __shared__ float cred[4][64];

    const int b  = blockIdx.y;
    const int n0 = blockIdx.x * 64;
    const int t = threadIdx.x, lane = t & 63, w = t >> 6;
    const size_t baseq = (size_t)b * NN * CC;
    const size_t basek = ((size_t)b * NN + n0) * CC;

    const int lr4 = lane >> 2;
    const int lc8 = (lane & 3) * 8;
    const int fr  = lane & 15;
    const int fk  = (lane >> 4) * 8;
    const int g4  = lane >> 4;

    float csum[4] = {0.f, 0.f, 0.f, 0.f};

    for (int m0 = 0; m0 < NN; m0 += 128) {
        if (t < 128) rho_s[t] = rho[(size_t)b * NN + m0 + t];

        floatx4 acc[2][4];
#pragma unroll
        for (int i = 0; i < 2; ++i)
#pragma unroll
            for (int j = 0; j < 4; ++j) acc[i][j] = (floatx4){0.f, 0.f, 0.f, 0.f};

        for (int kt = 0; kt < CC; kt += 32) {
            // stage Q 128x32 (wave w: rows w*32..+31)
#pragma unroll
            for (int c = 0; c < 2; ++c) {
                const int r = w * 32 + c * 16 + lr4;
                const size_t go = baseq + (size_t)(m0 + r) * CC + kt + lc8;
                GLD16(qh + go, sQh + (w * 32 + c * 16) * 32);
                GLD16(ql + go, sQl + (w * 32 + c * 16) * 32);
            }
            // stage K 64x32 (wave w: rows w*16..+15)
            {
                const size_t go = basek + (size_t)(w * 16 + lr4) * CC + kt + lc8;
                GLD16(kh + go, sKh + (w * 16) * 32);
                GLD16(kl + go, sKl + (w * 16) * 32);
            }
            __syncthreads();

            half8 ah[2], al[2], bh[4], bl[4];
#pragma unroll
            for (int rt = 0; rt < 2; ++rt) {
                ah[rt] = *(const half8*)&sQh[(w * 32 + rt * 16 + fr) * 32 + fk];
                al[rt] = *(const half8*)&sQl[(w * 32 + rt * 16 + fr) * 32 + fk];
            }
#pragma unroll
            for (int ct = 0; ct < 4; ++ct) {
                bh[ct] = *(const half8*)&sKh[(ct * 16 + fr) * 32 + fk];
                bl[ct] = *(const half8*)&sKl[(ct * 16 + fr) * 32 + fk];
            }
#pragma unroll
            for (int rt = 0; rt < 2; ++rt)
#pragma unroll
                for (int ct = 0; ct < 4; ++ct) {
                    acc[rt][ct] = __builtin_amdgcn_mfma_f32_16x16x32_f16(
                        ah[rt], bh[ct], acc[rt][ct], 0, 0, 0);
                    acc[rt][ct] = __builtin_amdgcn_mfma_f32_16x16x32_f16(
                        ah[rt], bl[ct], acc[rt][ct], 0, 0, 0);
                    acc[rt][ct] = __builtin_amdgcn_mfma_f32_16x16x32_f16(
                        al[rt], bh[ct], acc[rt][ct], 0, 0, 0);
                }
            __syncthreads();
        }

        // accumulate exp(s - rho[m]) into per-col register sums
#pragma unroll
        for (int rt = 0; rt < 2; ++rt)
#pragma unroll
            for (int reg = 0; reg < 4; ++reg) {
                const int row = w * 32 + rt * 16 + g4 * 4 + reg;
                const float r = rho_s[row];
#pragma unroll
                for (int ct = 0; ct < 4; ++ct)
                    csum[ct] += __expf(acc[rt][ct][reg] - r);
            }
        __syncthreads();   // rho_s reads done before next chunk overwrites
    }

    // reduce across the 4 row-groups within the wave, then across waves
#pragma unroll
    for (int ct = 0; ct < 4; ++ct) {
        csum[ct] += __shfl_xor(csum[ct], 16);
        csum[ct] += __shfl_xor(csum[ct], 32);
    }
    if (lane < 16)
#pragma unroll
        for (int ct = 0; ct < 4; ++ct) cred[w][ct * 16 + lane] = csum[ct];
    __syncthreads();
    if (t < 64) {
        const float s = cred[0][t] + cred[1][t] + cred[2][t] + cred[3][t];
        colsc[(size_t)b * NN + n0 + t] = s / (1e-9f + s);
    }
}

// ---------------------------------------------------------------------------
// Workspace (ws >= 128.4 MiB, same footprint as round 1):
//   qh|ql|kh|kl : 4 x M*C f16 = 128 MiB,  rho|colsc : 2 x M f32 = 256 KiB
//   tbuf (M*C f32, 64 MiB) aliases qh/ql after attention passes complete.
// ---------------------------------------------------------------------------
extern "C" void kernel_launch(void* const* d_in, const int* in_sizes, int n_in,
                              void* d_out, int out_size, void* d_ws, size_t ws_size,
                              hipStream_t stream)
{
    const float* x        = (const float*)d_in[0];
    const float* Wq       = (const float*)d_in[1];
    const float* bq       = (const float*)d_in[2];
    const float* Wk       = (const float*)d_in[3];
    const float* bk       = (const float*)d_in[4];
    const float* Wv       = (const float*)d_in[5];
    const float* bv       = (const float*)d_in[6];
    const float* Wo       = (const float*)d_in[7];
    const float* bo       = (const float*)d_in[8];
    const float* bn_scale = (const float*)d_in[9];
    const float* bn_bias  = (const float*)d_in[10];
    const float* bn_mean  = (const float*)d_in[11];
    const float* bn_var   = (const float*)d_in[12];
    float* out = (float*)d_out;

    const size_t MMC = (size_t)MM * CC;
    _Float16* qh = (_Float16*)d_ws;
    _Float16* ql = qh + MMC;
    _Float16* kh = ql + MMC;
    _Float16* kl = kh + MMC;
    float* rho   = (float*)(kl + MMC);
    float* colsc = rho + MM;
    float* tbuf  = (float*)d_ws;   // aliases qh/ql after attention

    const dim3 blk(256);
    const dim3 gproj(MM / TILE, CC / TILE);   // 512 x 8
    const dim3 gattn(NN / 64, BB);            // 32 x 16

    // q,k projections with fused hi/lo f16 split epilogue
    gemm_ep<<<gproj, blk, 0, stream>>>(x, Wq, bq, nullptr, nullptr, nullptr,
                                       nullptr, nullptr, nullptr, nullptr,
                                       qh, ql, CC, CC, 3);
    gemm_ep<<<gproj, blk, 0, stream>>>(x, Wk, bk, nullptr, nullptr, nullptr,
                                       nullptr, nullptr, nullptr, nullptr,
                                       kh, kl, CC, CC, 3);
    // MFMA attention passes
    attn_rowstats<<<gattn, blk, 0, stream>>>(qh, ql, kh, kl, rho);
    attn_colsum<<<gattn, blk, 0, stream>>>(qh, ql, kh, kl, rho, colsc);
    // t = colsc[r] * (x@Wv + bv)
    gemm_ep<<<gproj, blk, 0, stream>>>(x, Wv, bv, colsc, nullptr, nullptr,
                                       nullptr, nullptr, nullptr, tbuf,
                                       nullptr, nullptr, CC, CC, 1);
    // out = relu(BN(t@Wo + bo)) + x
    gemm_ep<<<gproj, blk, 0, stream>>>(tbuf, Wo, bo, nullptr, bn_scale, bn_bias,
                                       bn_mean, bn_var, x, out,
                                       nullptr, nullptr, CC, CC, 2);
}

// Round 3
// 774.978 us; speedup vs baseline: 4.4262x; 2.2081x over previous
//
#include <hip/hip_runtime.h>
#include <math.h>

// Problem constants (B=16, N=2048, C=512)
#define BB 16
#define NN 2048
#define CC 512
#define MM (BB * NN)   // 32768 flattened rows

typedef _Float16 half8 __attribute__((ext_vector_type(8)));
typedef _Float16 half4 __attribute__((ext_vector_type(4)));
typedef float floatx4 __attribute__((ext_vector_type(4)));

// async global->LDS, 16B/lane; LDS dest = wave-uniform base + lane*16
#define GLD16(gp, lp) __builtin_amdgcn_global_load_lds( \
    (const __attribute__((address_space(1))) void*)(gp), \
    (__attribute__((address_space(3))) void*)(lp), 16, 0, 0)

// LDS tile layout: 16-row groups, 32 halves (64B) per row, quad(16B)-XOR-swizzled:
// slot quad q' holds global quad q' ^ ((row>>1)&3)  -> b128 frag reads are 2-way
// conflict (free) instead of 8-way. Same XOR on stage & read (self-inverse).
__device__ __forceinline__ int foff(int row16base, int fr, int g4) {
    return (row16base + fr) * 32 + ((g4 ^ ((fr >> 1) & 3)) << 3);
}

// ---------------------------------------------------------------------------
// split x (fp32) -> xh + xl (f16 hi/lo), elementwise, float4-vectorized
// ---------------------------------------------------------------------------
__global__ __launch_bounds__(256)
void split_x(const float* __restrict__ x, _Float16* __restrict__ xh,
             _Float16* __restrict__ xl)
{
    const size_t i = ((size_t)blockIdx.x * 256 + threadIdx.x) * 4;
    const float4 v = *(const float4*)(x + i);
    half4 h, l;
    h[0] = (_Float16)v.x; l[0] = (_Float16)(v.x - (float)h[0]);
    h[1] = (_Float16)v.y; l[1] = (_Float16)(v.y - (float)h[1]);
    h[2] = (_Float16)v.z; l[2] = (_Float16)(v.z - (float)h[2]);
    h[3] = (_Float16)v.w; l[3] = (_Float16)(v.w - (float)h[3]);
    *(half4*)(xh + i) = h;
    *(half4*)(xl + i) = l;
}

// ---------------------------------------------------------------------------
// Wt[n*512+k] = f16(W[k*512+n])  (512x512 transpose+convert, tiny)
// ---------------------------------------------------------------------------
__global__ __launch_bounds__(256)
void conv_wT(const float* __restrict__ W, _Float16* __restrict__ Wt)
{
    const int o = blockIdx.x * 256 + threadIdx.x;   // o = n*512 + k
    const int n = o >> 9, k = o & 511;
    Wt[o] = (_Float16)W[k * 512 + n];
}

// ---------------------------------------------------------------------------
// w2[c] = sum_j Wk[c][j] * bq[j]   (beta helper; bq==0 at runtime)
// ---------------------------------------------------------------------------
__global__ __launch_bounds__(256)
void calc_w2(const float* __restrict__ Wk, const float* __restrict__ bq,
             float* __restrict__ w2)
{
    const int i = blockIdx.x * 256 + threadIdx.x;
    if (i < 512) {
        float s = 0.0f;
        for (int j = 0; j < 512; ++j) s += Wk[i * 512 + j] * bq[j];
        w2[i] = s;
    }
}

// ---------------------------------------------------------------------------
// bet[m] = x_m . w2   (one wave per row)
// ---------------------------------------------------------------------------
__global__ __launch_bounds__(256)
void calc_beta(const float* __restrict__ x, const float* __restrict__ w2,
               float* __restrict__ bet)
{
    const int w = threadIdx.x >> 6, lane = threadIdx.x & 63;
    const int m = blockIdx.x * 4 + w;
    const float* xr = x + (size_t)m * CC;
    float s = 0.0f;
    for (int c = lane; c < CC; c += 64) s += xr[c] * w2[c];
    for (int off = 1; off < 64; off <<= 1) s += __shfl_xor(s, off);
    if (lane == 0) bet[m] = s;
}

// ---------------------------------------------------------------------------
// Pt[j][i] = sum_c Wk[j][c]*Wq[i][c]  (= P^T, P = Wq Wk^T), fp32, split-store.
// Both operands staged row-wise (NT GEMM). 64x64 tile, grid (8,8).
// ---------------------------------------------------------------------------
__global__ __launch_bounds__(256)
void gemm_nt_split(const float* __restrict__ A, const float* __restrict__ Bm,
                   _Float16* __restrict__ outh, _Float16* __restrict__ outl)
{
    __shared__ float As[16][64];
    __shared__ float Bs[16][64];
    const int t = threadIdx.x, tc = t & 15, tr = t >> 4;
    const int j0 = blockIdx.x * 64, i0 = blockIdx.y * 64;
    const int lm = t >> 2, lk4 = (t & 3) << 2;
    float acc[4][4] = {};
    for (int kt = 0; kt < 512; kt += 16) {
        const float4 xa = *(const float4*)(A + (size_t)(j0 + lm) * 512 + kt + lk4);
        As[lk4 + 0][lm] = xa.x; As[lk4 + 1][lm] = xa.y;
        As[lk4 + 2][lm] = xa.z; As[lk4 + 3][lm] = xa.w;
        const float4 xb = *(const float4*)(Bm + (size_t)(i0 + lm) * 512 + kt + lk4);
        Bs[lk4 + 0][lm] = xb.x; Bs[lk4 + 1][lm] = xb.y;
        Bs[lk4 + 2][lm] = xb.z; Bs[lk4 + 3][lm] = xb.w;
        __syncthreads();
#pragma unroll
        for (int k = 0; k < 16; ++k) {
            float av[4], bv[4];
            *(float4*)av = *(const float4*)&As[k][tr * 4];
            *(float4*)bv = *(const float4*)&Bs[k][tc * 4];
#pragma unroll
            for (int i = 0; i < 4; ++i)
#pragma unroll
                for (int j = 0; j < 4; ++j)
                    acc[i][j] = fmaf(av[i], bv[j], acc[i][j]);
        }
        __syncthreads();
    }
#pragma unroll
    for (int i = 0; i < 4; ++i) {
        const int row = j0 + tr * 4 + i;
#pragma unroll
        for (int j = 0; j < 4; ++j) {
            const int col = i0 + tc * 4 + j;
            const float y = acc[i][j];
            const _Float16 h = (_Float16)y;
            outh[row * 512 + col] = h;
            outl[row * 512 + col] = (_Float16)(y - (float)h);
        }
    }
}

// ---------------------------------------------------------------------------
// f16 MFMA GEMM: Y[M x 512] = A[M x 512] @ Bt^T (Bt row n holds B col n).
// SPLIT: 3-term hi/lo (fp32-quality). 128x128 tile, 4 waves, 4x4 of 16x16x32.
// MODE 0: split-store oh/ol (a-GEMM)
// MODE 1: oh = f16((acc + bias[col]) * colsc[row])            (v-GEMM)
// MODE 2: outf = relu(BN(acc + bias)) + xres                  (out-GEMM)
// ---------------------------------------------------------------------------
template<bool SPLIT, int MODE>
__global__ __launch_bounds__(256)
void gemm16(const _Float16* __restrict__ Ah, const _Float16* __restrict__ Al,
            const _Float16* __restrict__ Bh, const _Float16* __restrict__ Bl,
            const float* __restrict__ bias, const float* __restrict__ colsc,
            const float* __restrict__ bn_scale, const float* __restrict__ bn_bias,
            const float* __restrict__ bn_mean, const float* __restrict__ bn_var,
            const float* __restrict__ xres,
            _Float16* __restrict__ oh, _Float16* __restrict__ ol,
            float* __restrict__ outf)
{
    __shared__ __align__(16) _Float16 sAh[128 * 32], sBh[128 * 32];
    __shared__ __align__(16) _Float16 sAl[128 * 32], sBl[128 * 32];

    const int t = threadIdx.x, lane = t & 63, w = t >> 6;
    const int m0 = blockIdx.x * 128, n0 = blockIdx.y * 128;
    const int lr4 = lane >> 2;
    const int sw8 = (((lane & 3) ^ ((lr4 >> 1) & 3)) << 3);  // swizzled quad
    const int fr = lane & 15, g4 = lane >> 4;
    const int wr = (w >> 1) * 64, wc = (w & 1) * 64;

    floatx4 acc[4][4];
#pragma unroll
    for (int i = 0; i < 4; ++i)
#pragma unroll
        for (int j = 0; j < 4; ++j) acc[i][j] = (floatx4){0.f, 0.f, 0.f, 0.f};

    for (int kt = 0; kt < CC; kt += 32) {
#pragma unroll
        for (int c = 0; c < 2; ++c) {
            const int r = w * 32 + c * 16;
            const size_t goA = (size_t)(m0 + r + lr4) * CC + kt + sw8;
            const size_t goB = (size_t)(n0 + r + lr4) * CC + kt + sw8;
            GLD16(Ah + goA, sAh + r * 32);
            GLD16(Bh + goB, sBh + r * 32);
            if constexpr (SPLIT) {
                GLD16(Al + goA, sAl + r * 32);
                GLD16(Bl + goB, sBl + r * 32);
            }
        }
        __syncthreads();

        half8 fa[4], fb[4], fal[4], fbl[4];
#pragma unroll
        for (int rt = 0; rt < 4; ++rt) {
            fa[rt] = *(const half8*)&sAh[foff(wr + rt * 16, fr, g4)];
            if constexpr (SPLIT) fal[rt] = *(const half8*)&sAl[foff(wr + rt * 16, fr, g4)];
        }
#pragma unroll
        for (int ct = 0; ct < 4; ++ct) {
            fb[ct] = *(const half8*)&sBh[foff(wc + ct * 16, fr, g4)];
            if constexpr (SPLIT) fbl[ct] = *(const half8*)&sBl[foff(wc + ct * 16, fr, g4)];
        }
#pragma unroll
        for (int rt = 0; rt < 4; ++rt)
#pragma unroll
            for (int ct = 0; ct < 4; ++ct) {
                acc[rt][ct] = __builtin_amdgcn_mfma_f32_16x16x32_f16(
                    fa[rt], fb[ct], acc[rt][ct], 0, 0, 0);
                if constexpr (SPLIT) {
                    acc[rt][ct] = __builtin_amdgcn_mfma_f32_16x16x32_f16(
                        fa[rt], fbl[ct], acc[rt][ct], 0, 0, 0);
                    acc[rt][ct] = __builtin_amdgcn_mfma_f32_16x16x32_f16(
                        fal[rt], fb[ct], acc[rt][ct], 0, 0, 0);
                }
            }
        __syncthreads();
    }

#pragma unroll
    for (int rt = 0; rt < 4; ++rt)
#pragma unroll
        for (int ct = 0; ct < 4; ++ct) {
            const int col = n0 + wc + ct * 16 + fr;
#pragma unroll
            for (int reg = 0; reg < 4; ++reg) {
                const int row = m0 + wr + rt * 16 + g4 * 4 + reg;
                float y = acc[rt][ct][reg];
                if constexpr (MODE == 0) {
                    const _Float16 h = (_Float16)y;
                    oh[(size_t)row * CC + col] = h;
                    ol[(size_t)row * CC + col] = (_Float16)(y - (float)h);
                } else if constexpr (MODE == 1) {
                    y = (y + bias[col]) * colsc[row];
                    oh[(size_t)row * CC + col] = (_Float16)y;
                } else {
                    y += bias[col];
                    y = (y - bn_mean[col]) * rsqrtf(bn_var[col] + 1e-5f)
                            * bn_scale[col] + bn_bias[col];
                    y = fmaxf(y, 0.0f) + xres[(size_t)row * CC + col];
                    outf[(size_t)row * CC + col] = y;
                }
            }
        }
}

// ---------------------------------------------------------------------------
// Pass A: rho[m] = logsumexp_n( (a_m . x_n) + bet[n] )  per batch.
// Block: 64 m-rows; n-chunks of 256; wave w covers cols [w*64, w*64+64).
// In-register online (m,l) per (row,col-lane); merged once at the end.
// ---------------------------------------------------------------------------
__global__ __launch_bounds__(256, 2)
void attn_rowstats(const _Float16* __restrict__ ah_, const _Float16* __restrict__ al_,
                   const _Float16* __restrict__ xh_, const _Float16* __restrict__ xl_,
                   const float* __restrict__ bet, float* __restrict__ rho)
{
    __shared__ __align__(16) _Float16 sAh[64 * 32], sAl[64 * 32];
    __shared__ __align__(16) _Float16 sXh[256 * 32], sXl[256 * 32];
    __shared__ float bet_s[256];
    __shared__ float wm[4][64], wl[4][64];

    const int b = blockIdx.y, m0 = blockIdx.x * 64;
    const int t = threadIdx.x, lane = t & 63, w = t >> 6;
    const size_t basea = ((size_t)b * NN + m0) * CC;
    const size_t basex = (size_t)b * NN * CC;
    const int lr4 = lane >> 2;
    const int sw8 = (((lane & 3) ^ ((lr4 >> 1) & 3)) << 3);
    const int fr = lane & 15, g4 = lane >> 4;

    float m_st[4][4], l_st[4][4];
#pragma unroll
    for (int i = 0; i < 4; ++i)
#pragma unroll
        for (int j = 0; j < 4; ++j) { m_st[i][j] = -3.0e38f; l_st[i][j] = 0.0f; }

    for (int n0 = 0; n0 < NN; n0 += 256) {
        bet_s[t] = bet[(size_t)b * NN + n0 + t];

        floatx4 acc[4][4];
#pragma unroll
        for (int i = 0; i < 4; ++i)
#pragma unroll
            for (int j = 0; j < 4; ++j) acc[i][j] = (floatx4){0.f, 0.f, 0.f, 0.f};

        for (int kt = 0; kt < CC; kt += 32) {
            {   // A: 64 rows, wave w stages rows w*16..+15 (hi & lo)
                const size_t go = basea + (size_t)(w * 16 + lr4) * CC + kt + sw8;
                GLD16(ah_ + go, sAh + (w * 16) * 32);
                GLD16(al_ + go, sAl + (w * 16) * 32);
            }
#pragma unroll
            for (int c = 0; c < 4; ++c) {   // X: 256 rows, wave w rows w*64+c*16
                const int r = w * 64 + c * 16;
                const size_t go = basex + (size_t)(n0 + r + lr4) * CC + kt + sw8;
                GLD16(xh_ + go, sXh + r * 32);
                GLD16(xl_ + go, sXl + r * 32);
            }
            __syncthreads();

            half8 fa[4], fal[4], fb[4], fbl[4];
#pragma unroll
            for (int rt = 0; rt < 4; ++rt) {
                fa[rt]  = *(const half8*)&sAh[foff(rt * 16, fr, g4)];
                fal[rt] = *(const half8*)&sAl[foff(rt * 16, fr, g4)];
            }
#pragma unroll
            for (int ct = 0; ct < 4; ++ct) {
                fb[ct]  = *(const half8*)&sXh[foff(w * 64 + ct * 16, fr, g4)];
                fbl[ct] = *(const half8*)&sXl[foff(w * 64 + ct * 16, fr, g4)];
            }
#pragma unroll
            for (int rt = 0; rt < 4; ++rt)
#pragma unroll
                for (int ct = 0; ct < 4; ++ct) {
                    acc[rt][ct] = __builtin_amdgcn_mfma_f32_16x16x32_f16(
                        fa[rt], fb[ct], acc[rt][ct], 0, 0, 0);
                    acc[rt][ct] = __builtin_amdgcn_mfma_f32_16x16x32_f16(
                        fa[rt], fbl[ct], acc[rt][ct], 0, 0, 0);
                    acc[rt][ct] = __builtin_amdgcn_mfma_f32_16x16x32_f16(
                        fal[rt], fb[ct], acc[rt][ct], 0, 0, 0);
                }
            __syncthreads();
        }

        // in-register online softmax update (per row, this lane's 4 cols)
#pragma unroll
        for (int rt = 0; rt < 4; ++rt)
#pragma unroll
            for (int reg = 0; reg < 4; ++reg) {
                float v0 = acc[rt][0][reg] + bet_s[w * 64 +  0 + fr];
                float v1 = acc[rt][1][reg] + bet_s[w * 64 + 16 + fr];
                float v2 = acc[rt][2][reg] + bet_s[w * 64 + 32 + fr];
                float v3 = acc[rt][3][reg] + bet_s[w * 64 + 48 + fr];
                const float mx = fmaxf(fmaxf(v0, v1), fmaxf(v2, v3));
                const float mo = m_st[rt][reg];
                const float mn = fmaxf(mo, mx);
                const float s = __expf(v0 - mn) + __expf(v1 - mn)
                              + __expf(v2 - mn) + __expf(v3 - mn);
                l_st[rt][reg] = l_st[rt][reg] * __expf(mo - mn) + s;
                m_st[rt][reg] = mn;
            }
        __syncthreads();   // protect bet_s before next chunk's store
    }

    // merge across 16 col-lanes (xor 1,2,4,8), then across 4 waves via LDS
#pragma unroll
    for (int rt = 0; rt < 4; ++rt)
#pragma unroll
        for (int reg = 0; reg < 4; ++reg) {
            float m = m_st[rt][reg], l = l_st[rt][reg];
#pragma unroll
            for (int off = 1; off < 16; off <<= 1) {
                const float mo = __shfl_xor(m, off);
                const float lo = __shfl_xor(l, off);
                const float mn = fmaxf(m, mo);
                l = l * __expf(m - mn) + lo * __expf(mo - mn);
                m = mn;
            }
            if (fr == 0) {
                wm[w][rt * 16 + g4 * 4 + reg] = m;
                wl[w][rt * 16 + g4 * 4 + reg] = l;
            }
        }
    __syncthreads();
    if (t < 64) {
        float M = fmaxf(fmaxf(wm[0][t], wm[1][t]), fmaxf(wm[2][t], wm[3][t]));
        float L = wl[0][t] * __expf(wm[0][t] - M) + wl[1][t] * __expf(wm[1][t] - M)
                + wl[2][t] * __expf(wm[2][t] - M) + wl[3][t] * __expf(wm[3][t] - M);
        rho[(size_t)b * NN + m0 + t] = M + __logf(L);
    }
}

// ---------------------------------------------------------------------------
// Pass B: colsc[n] = c/(eps+c), c = sum_m exp( (a_m . x_n) + bet[n] - rho[m] ).
// Block: 64 n-cols; m-chunks of 256; wave w covers rows [w*64, w*64+64).
// ---------------------------------------------------------------------------
__global__ __launch_bounds__(256, 2)
void attn_colsum(const _Float16* __restrict__ ah_, const _Float16* __restrict__ al_,
                 const _Float16* __restrict__ xh_, const _Float16* __restrict__ xl_,
                 const float* __restrict__ bet, const float* __restrict__ rho,
                 float* __restrict__ colsc)
{
    __shared__ __align__(16) _Float16 sAh[256 * 32], sAl[256 * 32];
    __shared__ __align__(16) _Float16 sXh[64 * 32], sXl[64 * 32];
    __shared__ float rho_s[256];
    __shared__ float bet_s[64];
    __shared__ float cred[4][64];

    const int b = blockIdx.y, n0 = blockIdx.x * 64;
    const int t = threadIdx.x, lane = t & 63, w = t >> 6;
    const size_t basea = (size_t)b * NN * CC;
    const size_t basex = ((size_t)b * NN + n0) * CC;
    const int lr4 = lane >> 2;
    const int sw8 = (((lane & 3) ^ ((lr4 >> 1) & 3)) << 3);
    const int fr = lane & 15, g4 = lane >> 4;

    if (t < 64) bet_s[t] = bet[(size_t)b * NN + n0 + t];
    float csum[4] = {0.f, 0.f, 0.f, 0.f};

    for (int m0 = 0; m0 < NN; m0 += 256) {
        rho_s[t] = rho[(size_t)b * NN + m0 + t];

        floatx4 acc[4][4];
#pragma unroll
        for (int i = 0; i < 4; ++i)
#pragma unroll
            for (int j = 0; j < 4; ++j) acc[i][j] = (floatx4){0.f, 0.f, 0.f, 0.f};

        for (int kt = 0; kt < CC; kt += 32) {
#pragma unroll
            for (int c = 0; c < 4; ++c) {   // A: 256 rows, wave w rows w*64+c*16
                const int r = w * 64 + c * 16;
                const size_t go = basea + (size_t)(m0 + r + lr4) * CC + kt + sw8;
                GLD16(ah_ + go, sAh + r * 32);
                GLD16(al_ + go, sAl + r * 32);
            }
            {   // X: 64 rows, wave w stages rows w*16..+15
                const size_t go = basex + (size_t)(w * 16 + lr4) * CC + kt + sw8;
                GLD16(xh_ + go, sXh + (w * 16) * 32);
                GLD16(xl_ + go, sXl + (w * 16) * 32);
            }
            __syncthreads();

            half8 fa[4], fal[4], fb[4], fbl[4];
#pragma unroll
            for (int rt = 0; rt < 4; ++rt) {
                fa[rt]  = *(const half8*)&sAh[foff(w * 64 + rt * 16, fr, g4)];
                fal[rt] = *(const half8*)&sAl[foff(w * 64 + rt * 16, fr, g4)];
            }
#pragma unroll
            for (int ct = 0; ct < 4; ++ct) {
                fb[ct]  = *(const half8*)&sXh[foff(ct * 16, fr, g4)];
                fbl[ct] = *(const half8*)&sXl[foff(ct * 16, fr, g4)];
            }
#pragma unroll
            for (int rt = 0; rt < 4; ++rt)
#pragma unroll
                for (int ct = 0; ct < 4; ++ct) {
                    acc[rt][ct] = __builtin_amdgcn_mfma_f32_16x16x32_f16(
                        fa[rt], fb[ct], acc[rt][ct], 0, 0, 0);
                    acc[rt][ct] = __builtin_amdgcn_mfma_f32_16x16x32_f16(
                        fa[rt], fbl[ct], acc[rt][ct], 0, 0, 0);
                    acc[rt][ct] = __builtin_amdgcn_mfma_f32_16x16x32_f16(
                        fal[rt], fb[ct], acc[rt][ct], 0, 0, 0);
                }
            __syncthreads();
        }

        // accumulate exp(s + bet[n] - rho[m]) into per-col register sums
#pragma unroll
        for (int rt = 0; rt < 4; ++rt)
#pragma unroll
            for (int reg = 0; reg < 4; ++reg) {
                const int row = w * 64 + rt * 16 + g4 * 4 + reg;
                const float r = rho_s[row];
#pragma unroll
                for (int ct = 0; ct < 4; ++ct)
                    csum[ct] += __expf(acc[rt][ct][reg] + bet_s[ct * 16 + fr] - r);
            }
        __syncthreads();   // protect rho_s before next chunk's store
    }

    // reduce over row-lane groups, then across waves
#pragma unroll
    for (int ct = 0; ct < 4; ++ct) {
        csum[ct] += __shfl_xor(csum[ct], 16);
        csum[ct] += __shfl_xor(csum[ct], 32);
    }
    if (lane < 16)
#pragma unroll
        for (int ct = 0; ct < 4; ++ct) cred[w][ct * 16 + lane] = csum[ct];
    __syncthreads();
    if (t < 64) {
        const float s = cred[0][t] + cred[1][t] + cred[2][t] + cred[3][t];
        colsc[(size_t)b * NN + n0 + t] = s / (1e-9f + s);
    }
}

// ---------------------------------------------------------------------------
// Workspace (ws, exactly 128 MiB <= round-1-proven 128.4 MiB):
//   xh|xl|ah|al : 4 x M*C f16.  After passB: Wvt/Wot converted into ah's
//   region (dead); th aliases al.  Small scratch (P split, w2, bet, rho,
//   colsc) lives in d_out, which is only written by the final GEMM.
// ---------------------------------------------------------------------------
extern "C" void kernel_launch(void* const* d_in, const int* in_sizes, int n_in,
                              void* d_out, int out_size, void* d_ws, size_t ws_size,
                              hipStream_t stream)
{
    const float* x        = (const float*)d_in[0];
    const float* Wq       = (const float*)d_in[1];
    const float* bq       = (const float*)d_in[2];
    const float* Wk       = (const float*)d_in[3];
    const float* bk       = (const float*)d_in[4];   (void)bk;  // softmax-invariant
    const float* Wv       = (const float*)d_in[5];
    const float* bv       = (const float*)d_in[6];
    const float* Wo       = (const float*)d_in[7];
    const float* bo       = (const float*)d_in[8];
    const float* bn_scale = (const float*)d_in[9];
    const float* bn_bias  = (const float*)d_in[10];
    const float* bn_mean  = (const float*)d_in[11];
    const float* bn_var   = (const float*)d_in[12];
    float* out = (float*)d_out;

    const size_t MMC = (size_t)MM * CC;   // 16,777,216
    _Float16* xh = (_Float16*)d_ws;
    _Float16* xl = xh + MMC;
    _Float16* ah = xl + MMC;
    _Float16* al = ah + MMC;
    _Float16* th  = al;                    // v-GEMM output aliases al
    _Float16* Wvt = ah;                    // converted after passB (ah dead)
    _Float16* Wot = ah + 512 * 512;

    // small scratch in d_out (dead before the final GEMM writes d_out)
    char* ob = (char*)d_out;
    _Float16* Pth = (_Float16*)(ob);                    //   512 KiB
    _Float16* Ptl = (_Float16*)(ob + 524288);           //   512 KiB
    float* w2     = (float*)(ob + 1048576);             //     2 KiB
    float* bet    = (float*)(ob + 1052672);             //   128 KiB
    float* rho    = (float*)(ob + 1183744);             //   128 KiB
    float* colsc  = (float*)(ob + 1314816);             //   128 KiB

    const dim3 blk(256);
    const dim3 g16(MM / 128, CC / 128);   // 256 x 4
    const dim3 gattn(NN / 64, BB);        // 32 x 16

    split_x<<<MMC / (256 * 4), blk, 0, stream>>>(x, xh, xl);
    gemm_nt_split<<<dim3(8, 8), blk, 0, stream>>>(Wk, Wq, Pth, Ptl);
    calc_w2<<<2, blk, 0, stream>>>(Wk, bq, w2);
    calc_beta<<<MM / 4, blk, 0, stream>>>(x, w2, bet);

    // a = x @ (Wq Wk^T), split-stored
    gemm16<true, 0><<<g16, blk, 0, stream>>>(xh, xl, Pth, Ptl,
        nullptr, nullptr, nullptr, nullptr, nullptr, nullptr, nullptr,
        ah, al, nullptr);

    attn_rowstats<<<gattn, blk, 0, stream>>>(ah, al, xh, xl, bet, rho);
    attn_colsum<<<gattn, blk, 0, stream>>>(ah, al, xh, xl, bet, rho, colsc);

    // th = f16(colsc[row] * (x @ Wv + bv))
    conv_wT<<<1024, blk, 0, stream>>>(Wv, Wvt);
    gemm16<false, 1><<<g16, blk, 0, stream>>>(xh, nullptr, Wvt, nullptr,
        bv, colsc, nullptr, nullptr, nullptr, nullptr, nullptr,
        th, nullptr, nullptr);

    // out = relu(BN(th @ Wo + bo)) + x
    conv_wT<<<1024, blk, 0, stream>>>(Wo, Wot);
    gemm16<false, 2><<<g16, blk, 0, stream>>>(th, nullptr, Wot, nullptr,
        bo, nullptr, bn_scale, bn_bias, bn_mean, bn_var, x,
        nullptr, nullptr, out);
}

// Round 4
// 679.923 us; speedup vs baseline: 5.0450x; 1.1398x over previous
//
#include <hip/hip_runtime.h>
#include <math.h>

// Problem constants (B=16, N=2048, C=512)
#define BB 16
#define NN 2048
#define CC 512
#define MM (BB * NN)   // 32768 flattened rows
#define NSPLIT 4       // range-split factor for attention passes

typedef _Float16 half8 __attribute__((ext_vector_type(8)));
typedef _Float16 half4 __attribute__((ext_vector_type(4)));
typedef float floatx4 __attribute__((ext_vector_type(4)));

// async global->LDS, 16B/lane; LDS dest = wave-uniform base + lane*16
#define GLD16(gp, lp) __builtin_amdgcn_global_load_lds( \
    (const __attribute__((address_space(1))) void*)(gp), \
    (__attribute__((address_space(3))) void*)(lp), 16, 0, 0)

// LDS tile layout: 16-row groups, 32 halves (64B) per row, quad(16B)-XOR-swizzled:
// slot quad q' holds global quad q' ^ ((row>>1)&3)  -> b128 frag reads are 2-way
// conflict (free) instead of 8-way. Same XOR on stage & read (self-inverse).
__device__ __forceinline__ int foff(int row16base, int fr, int g4) {
    return (row16base + fr) * 32 + ((g4 ^ ((fr >> 1) & 3)) << 3);
}

// ---------------------------------------------------------------------------
// split x (fp32) -> xh + xl (f16 hi/lo), elementwise, float4-vectorized
// ---------------------------------------------------------------------------
__global__ __launch_bounds__(256)
void split_x(const float* __restrict__ x, _Float16* __restrict__ xh,
             _Float16* __restrict__ xl)
{
    const size_t i = ((size_t)blockIdx.x * 256 + threadIdx.x) * 4;
    const float4 v = *(const float4*)(x + i);
    half4 h, l;
    h[0] = (_Float16)v.x; l[0] = (_Float16)(v.x - (float)h[0]);
    h[1] = (_Float16)v.y; l[1] = (_Float16)(v.y - (float)h[1]);
    h[2] = (_Float16)v.z; l[2] = (_Float16)(v.z - (float)h[2]);
    h[3] = (_Float16)v.w; l[3] = (_Float16)(v.w - (float)h[3]);
    *(half4*)(xh + i) = h;
    *(half4*)(xl + i) = l;
}

// ---------------------------------------------------------------------------
// Wt[n*512+k] = f16(W[k*512+n])  (512x512 transpose+convert, tiny)
// ---------------------------------------------------------------------------
__global__ __launch_bounds__(256)
void conv_wT(const float* __restrict__ W, _Float16* __restrict__ Wt)
{
    const int o = blockIdx.x * 256 + threadIdx.x;   // o = n*512 + k
    const int n = o >> 9, k = o & 511;
    Wt[o] = (_Float16)W[k * 512 + n];
}

// ---------------------------------------------------------------------------
// w2[c] = sum_j Wk[c][j] * bq[j]   (beta helper; bq==0 at runtime)
// ---------------------------------------------------------------------------
__global__ __launch_bounds__(256)
void calc_w2(const float* __restrict__ Wk, const float* __restrict__ bq,
             float* __restrict__ w2)
{
    const int i = blockIdx.x * 256 + threadIdx.x;
    if (i < 512) {
        float s = 0.0f;
        for (int j = 0; j < 512; ++j) s += Wk[i * 512 + j] * bq[j];
        w2[i] = s;
    }
}

// ---------------------------------------------------------------------------
// bet[m] = x_m . w2   (one wave per row)
// ---------------------------------------------------------------------------
__global__ __launch_bounds__(256)
void calc_beta(const float* __restrict__ x, const float* __restrict__ w2,
               float* __restrict__ bet)
{
    const int w = threadIdx.x >> 6, lane = threadIdx.x & 63;
    const int m = blockIdx.x * 4 + w;
    const float* xr = x + (size_t)m * CC;
    float s = 0.0f;
    for (int c = lane; c < CC; c += 64) s += xr[c] * w2[c];
    for (int off = 1; off < 64; off <<= 1) s += __shfl_xor(s, off);
    if (lane == 0) bet[m] = s;
}

// ---------------------------------------------------------------------------
// Pt[j][i] = sum_c Wk[j][c]*Wq[i][c]  (= P^T, P = Wq Wk^T), fp32, split-store.
// ---------------------------------------------------------------------------
__global__ __launch_bounds__(256)
void gemm_nt_split(const float* __restrict__ A, const float* __restrict__ Bm,
                   _Float16* __restrict__ outh, _Float16* __restrict__ outl)
{
    __shared__ float As[16][64];
    __shared__ float Bs[16][64];
    const int t = threadIdx.x, tc = t & 15, tr = t >> 4;
    const int j0 = blockIdx.x * 64, i0 = blockIdx.y * 64;
    const int lm = t >> 2, lk4 = (t & 3) << 2;
    float acc[4][4] = {};
    for (int kt = 0; kt < 512; kt += 16) {
        const float4 xa = *(const float4*)(A + (size_t)(j0 + lm) * 512 + kt + lk4);
        As[lk4 + 0][lm] = xa.x; As[lk4 + 1][lm] = xa.y;
        As[lk4 + 2][lm] = xa.z; As[lk4 + 3][lm] = xa.w;
        const float4 xb = *(const float4*)(Bm + (size_t)(i0 + lm) * 512 + kt + lk4);
        Bs[lk4 + 0][lm] = xb.x; Bs[lk4 + 1][lm] = xb.y;
        Bs[lk4 + 2][lm] = xb.z; Bs[lk4 + 3][lm] = xb.w;
        __syncthreads();
#pragma unroll
        for (int k = 0; k < 16; ++k) {
            float av[4], bv[4];
            *(float4*)av = *(const float4*)&As[k][tr * 4];
            *(float4*)bv = *(const float4*)&Bs[k][tc * 4];
#pragma unroll
            for (int i = 0; i < 4; ++i)
#pragma unroll
                for (int j = 0; j < 4; ++j)
                    acc[i][j] = fmaf(av[i], bv[j], acc[i][j]);
        }
        __syncthreads();
    }
#pragma unroll
    for (int i = 0; i < 4; ++i) {
        const int row = j0 + tr * 4 + i;
#pragma unroll
        for (int j = 0; j < 4; ++j) {
            const int col = i0 + tc * 4 + j;
            const float y = acc[i][j];
            const _Float16 h = (_Float16)y;
            outh[row * 512 + col] = h;
            outl[row * 512 + col] = (_Float16)(y - (float)h);
        }
    }
}

// ---------------------------------------------------------------------------
// f16 MFMA GEMM: Y[M x 512] = A[M x 512] @ Bt^T. 128x128 tile, 4 waves.
// MODE 0 (SPLIT): split-store oh/ol (a-GEMM, 3-term hi/lo)
// MODE 1: oh = f16((acc + bias[col]) * colsc[row])            (v-GEMM)
// MODE 2: outf = relu(BN(acc + bias)) + xres                  (out-GEMM)
// ---------------------------------------------------------------------------
template<bool SPLIT, int MODE>
__global__ __launch_bounds__(256)
void gemm16(const _Float16* __restrict__ Ah, const _Float16* __restrict__ Al,
            const _Float16* __restrict__ Bh, const _Float16* __restrict__ Bl,
            const float* __restrict__ bias, const float* __restrict__ colsc,
            const float* __restrict__ bn_scale, const float* __restrict__ bn_bias,
            const float* __restrict__ bn_mean, const float* __restrict__ bn_var,
            const float* __restrict__ xres,
            _Float16* __restrict__ oh, _Float16* __restrict__ ol,
            float* __restrict__ outf)
{
    __shared__ __align__(16) _Float16 sAh[128 * 32], sBh[128 * 32];
    __shared__ __align__(16) _Float16 sAl[128 * 32], sBl[128 * 32];

    const int t = threadIdx.x, lane = t & 63, w = t >> 6;
    const int m0 = blockIdx.x * 128, n0 = blockIdx.y * 128;
    const int lr4 = lane >> 2;
    const int sw8 = (((lane & 3) ^ ((lr4 >> 1) & 3)) << 3);
    const int fr = lane & 15, g4 = lane >> 4;
    const int wr = (w >> 1) * 64, wc = (w & 1) * 64;

    floatx4 acc[4][4];
#pragma unroll
    for (int i = 0; i < 4; ++i)
#pragma unroll
        for (int j = 0; j < 4; ++j) acc[i][j] = (floatx4){0.f, 0.f, 0.f, 0.f};

    for (int kt = 0; kt < CC; kt += 32) {
#pragma unroll
        for (int c = 0; c < 2; ++c) {
            const int r = w * 32 + c * 16;
            const size_t goA = (size_t)(m0 + r + lr4) * CC + kt + sw8;
            const size_t goB = (size_t)(n0 + r + lr4) * CC + kt + sw8;
            GLD16(Ah + goA, sAh + r * 32);
            GLD16(Bh + goB, sBh + r * 32);
            if constexpr (SPLIT) {
                GLD16(Al + goA, sAl + r * 32);
                GLD16(Bl + goB, sBl + r * 32);
            }
        }
        __syncthreads();

        half8 fa[4], fb[4], fal[4], fbl[4];
#pragma unroll
        for (int rt = 0; rt < 4; ++rt) {
            fa[rt] = *(const half8*)&sAh[foff(wr + rt * 16, fr, g4)];
            if constexpr (SPLIT) fal[rt] = *(const half8*)&sAl[foff(wr + rt * 16, fr, g4)];
        }
#pragma unroll
        for (int ct = 0; ct < 4; ++ct) {
            fb[ct] = *(const half8*)&sBh[foff(wc + ct * 16, fr, g4)];
            if constexpr (SPLIT) fbl[ct] = *(const half8*)&sBl[foff(wc + ct * 16, fr, g4)];
        }
#pragma unroll
        for (int rt = 0; rt < 4; ++rt)
#pragma unroll
            for (int ct = 0; ct < 4; ++ct) {
                acc[rt][ct] = __builtin_amdgcn_mfma_f32_16x16x32_f16(
                    fa[rt], fb[ct], acc[rt][ct], 0, 0, 0);
                if constexpr (SPLIT) {
                    acc[rt][ct] = __builtin_amdgcn_mfma_f32_16x16x32_f16(
                        fa[rt], fbl[ct], acc[rt][ct], 0, 0, 0);
                    acc[rt][ct] = __builtin_amdgcn_mfma_f32_16x16x32_f16(
                        fal[rt], fb[ct], acc[rt][ct], 0, 0, 0);
                }
            }
        __syncthreads();
    }

#pragma unroll
    for (int rt = 0; rt < 4; ++rt)
#pragma unroll
        for (int ct = 0; ct < 4; ++ct) {
            const int col = n0 + wc + ct * 16 + fr;
#pragma unroll
            for (int reg = 0; reg < 4; ++reg) {
                const int row = m0 + wr + rt * 16 + g4 * 4 + reg;
                float y = acc[rt][ct][reg];
                if constexpr (MODE == 0) {
                    const _Float16 h = (_Float16)y;
                    oh[(size_t)row * CC + col] = h;
                    ol[(size_t)row * CC + col] = (_Float16)(y - (float)h);
                } else if constexpr (MODE == 1) {
                    y = (y + bias[col]) * colsc[row];
                    oh[(size_t)row * CC + col] = (_Float16)y;
                } else {
                    y += bias[col];
                    y = (y - bn_mean[col]) * rsqrtf(bn_var[col] + 1e-5f)
                            * bn_scale[col] + bn_bias[col];
                    y = fmaxf(y, 0.0f) + xres[(size_t)row * CC + col];
                    outf[(size_t)row * CC + col] = y;
                }
            }
        }
}

// ---------------------------------------------------------------------------
// Pass A: partial online-softmax stats over an n-range of 512.
// Grid (m-tile 16, batch 16, split 4). Block: 128 m-rows x n-chunks of 128.
// 2-term: S = ah.x + al.x  (x single f16). Wave w: rows (w>>1)*64, cols (w&1)*64.
// Emits pm/pl [split][b*NN+m] (partial max / sumexp).
// ---------------------------------------------------------------------------
__global__ __launch_bounds__(256)
void attn_rowstats(const _Float16* __restrict__ ah_, const _Float16* __restrict__ al_,
                   const _Float16* __restrict__ xh_,
                   const float* __restrict__ bet,
                   float* __restrict__ pm, float* __restrict__ pl)
{
    __shared__ __align__(16) _Float16 sAh[128 * 32], sAl[128 * 32], sX[128 * 32];
    __shared__ float bet_s[128];
    __shared__ float wm[4][64], wl[4][64];

    const int b = blockIdx.y, m0 = blockIdx.x * 128, sp = blockIdx.z;
    const int t = threadIdx.x, lane = t & 63, w = t >> 6;
    const int lr4 = lane >> 2;
    const int sw8 = (((lane & 3) ^ ((lr4 >> 1) & 3)) << 3);
    const int fr = lane & 15, g4 = lane >> 4;
    const int wr = (w >> 1) * 64, wc = (w & 1) * 64;
    const size_t bbase = (size_t)b * NN;

    float m_st[4][4], l_st[4][4];
#pragma unroll
    for (int i = 0; i < 4; ++i)
#pragma unroll
        for (int j = 0; j < 4; ++j) { m_st[i][j] = -3.0e38f; l_st[i][j] = 0.0f; }

    for (int ch = 0; ch < 4; ++ch) {
        const int n0 = sp * 512 + ch * 128;
        if (t < 128) bet_s[t] = bet[bbase + n0 + t];

        floatx4 acc[4][4];
#pragma unroll
        for (int i = 0; i < 4; ++i)
#pragma unroll
            for (int j = 0; j < 4; ++j) acc[i][j] = (floatx4){0.f, 0.f, 0.f, 0.f};

        for (int kt = 0; kt < CC; kt += 32) {
#pragma unroll
            for (int c = 0; c < 2; ++c) {
                const int r = w * 32 + c * 16;
                const size_t goA = (bbase + m0 + r + lr4) * CC + kt + sw8;
                const size_t goX = (bbase + n0 + r + lr4) * CC + kt + sw8;
                GLD16(ah_ + goA, sAh + r * 32);
                GLD16(al_ + goA, sAl + r * 32);
                GLD16(xh_ + goX, sX + r * 32);
            }
            __syncthreads();

            half8 fa[4], fal[4], fb[4];
#pragma unroll
            for (int rt = 0; rt < 4; ++rt) {
                fa[rt]  = *(const half8*)&sAh[foff(wr + rt * 16, fr, g4)];
                fal[rt] = *(const half8*)&sAl[foff(wr + rt * 16, fr, g4)];
            }
#pragma unroll
            for (int ct = 0; ct < 4; ++ct)
                fb[ct] = *(const half8*)&sX[foff(wc + ct * 16, fr, g4)];
#pragma unroll
            for (int rt = 0; rt < 4; ++rt)
#pragma unroll
                for (int ct = 0; ct < 4; ++ct) {
                    acc[rt][ct] = __builtin_amdgcn_mfma_f32_16x16x32_f16(
                        fa[rt], fb[ct], acc[rt][ct], 0, 0, 0);
                    acc[rt][ct] = __builtin_amdgcn_mfma_f32_16x16x32_f16(
                        fal[rt], fb[ct], acc[rt][ct], 0, 0, 0);
                }
            __syncthreads();
        }

        // in-register online softmax update (per row, this lane's 4 cols)
#pragma unroll
        for (int rt = 0; rt < 4; ++rt)
#pragma unroll
            for (int reg = 0; reg < 4; ++reg) {
                const float v0 = acc[rt][0][reg] + bet_s[wc +  0 + fr];
                const float v1 = acc[rt][1][reg] + bet_s[wc + 16 + fr];
                const float v2 = acc[rt][2][reg] + bet_s[wc + 32 + fr];
                const float v3 = acc[rt][3][reg] + bet_s[wc + 48 + fr];
                const float mx = fmaxf(fmaxf(v0, v1), fmaxf(v2, v3));
                const float mo = m_st[rt][reg];
                const float mn = fmaxf(mo, mx);
                const float s = __expf(v0 - mn) + __expf(v1 - mn)
                              + __expf(v2 - mn) + __expf(v3 - mn);
                l_st[rt][reg] = l_st[rt][reg] * __expf(mo - mn) + s;
                m_st[rt][reg] = mn;
            }
        __syncthreads();   // protect bet_s before next chunk's store
    }

    // merge across 16 col-lanes, then across the col-wave pair via LDS
#pragma unroll
    for (int rt = 0; rt < 4; ++rt)
#pragma unroll
        for (int reg = 0; reg < 4; ++reg) {
            float m = m_st[rt][reg], l = l_st[rt][reg];
#pragma unroll
            for (int off = 1; off < 16; off <<= 1) {
                const float mo = __shfl_xor(m, off);
                const float lo = __shfl_xor(l, off);
                const float mn = fmaxf(m, mo);
                l = l * __expf(m - mn) + lo * __expf(mo - mn);
                m = mn;
            }
            if (fr == 0) {
                wm[w][rt * 16 + g4 * 4 + reg] = m;
                wl[w][rt * 16 + g4 * 4 + reg] = l;
            }
        }
    __syncthreads();
    if (t < 128) {
        const int r = t & 63;
        const int wa = (t < 64) ? 0 : 2, wb = wa + 1;
        const float ma = wm[wa][r], mb = wm[wb][r];
        const float M = fmaxf(ma, mb);
        const float L = wl[wa][r] * __expf(ma - M) + wl[wb][r] * __expf(mb - M);
        pm[(size_t)sp * MM + bbase + m0 + t] = M;
        pl[(size_t)sp * MM + bbase + m0 + t] = L;
    }
}

// ---------------------------------------------------------------------------
// rho[m] = M + log(sum_s pl[s]*exp(pm[s]-M)),  M = max_s pm[s]
// ---------------------------------------------------------------------------
__global__ __launch_bounds__(256)
void rho_merge(const float* __restrict__ pm, const float* __restrict__ pl,
               float* __restrict__ rho)
{
    const size_t i = (size_t)blockIdx.x * 256 + threadIdx.x;
    float M = pm[i];
#pragma unroll
    for (int s = 1; s < NSPLIT; ++s) M = fmaxf(M, pm[s * (size_t)MM + i]);
    float L = 0.0f;
#pragma unroll
    for (int s = 0; s < NSPLIT; ++s)
        L += pl[s * (size_t)MM + i] * __expf(pm[s * (size_t)MM + i] - M);
    rho[i] = M + __logf(L);
}

// ---------------------------------------------------------------------------
// Pass B: partial column sums over an m-range of 512.
// Grid (n-tile 16, batch 16, split 4). Block: 128 n-cols x m-chunks of 128.
// pc[split][b*NN+n] = sum_{m in range} exp(s + bet[n] - rho[m]).
// ---------------------------------------------------------------------------
__global__ __launch_bounds__(256)
void attn_colsum(const _Float16* __restrict__ ah_, const _Float16* __restrict__ al_,
                 const _Float16* __restrict__ xh_,
                 const float* __restrict__ bet, const float* __restrict__ rho,
                 float* __restrict__ pc)
{
    __shared__ __align__(16) _Float16 sAh[128 * 32], sAl[128 * 32], sX[128 * 32];
    __shared__ float rho_s[128], bet_s[128];
    __shared__ float cred[4][64];

    const int b = blockIdx.y, n0 = blockIdx.x * 128, sp = blockIdx.z;
    const int t = threadIdx.x, lane = t & 63, w = t >> 6;
    const int lr4 = lane >> 2;
    const int sw8 = (((lane & 3) ^ ((lr4 >> 1) & 3)) << 3);
    const int fr = lane & 15, g4 = lane >> 4;
    const int wr = (w >> 1) * 64, wc = (w & 1) * 64;
    const size_t bbase = (size_t)b * NN;

    if (t < 128) bet_s[t] = bet[bbase + n0 + t];
    float csum[4] = {0.f, 0.f, 0.f, 0.f};

    for (int ch = 0; ch < 4; ++ch) {
        const int m0 = sp * 512 + ch * 128;
        if (t < 128) rho_s[t] = rho[bbase + m0 + t];

        floatx4 acc[4][4];
#pragma unroll
        for (int i = 0; i < 4; ++i)
#pragma unroll
            for (int j = 0; j < 4; ++j) acc[i][j] = (floatx4){0.f, 0.f, 0.f, 0.f};

        for (int kt = 0; kt < CC; kt += 32) {
#pragma unroll
            for (int c = 0; c < 2; ++c) {
                const int r = w * 32 + c * 16;
                const size_t goA = (bbase + m0 + r + lr4) * CC + kt + sw8;
                const size_t goX = (bbase + n0 + r + lr4) * CC + kt + sw8;
                GLD16(ah_ + goA, sAh + r * 32);
                GLD16(al_ + goA, sAl + r * 32);
                GLD16(xh_ + goX, sX + r * 32);
            }
            __syncthreads();

            half8 fa[4], fal[4], fb[4];
#pragma unroll
            for (int rt = 0; rt < 4; ++rt) {
                fa[rt]  = *(const half8*)&sAh[foff(wr + rt * 16, fr, g4)];
                fal[rt] = *(const half8*)&sAl[foff(wr + rt * 16, fr, g4)];
            }
#pragma unroll
            for (int ct = 0; ct < 4; ++ct)
                fb[ct] = *(const half8*)&sX[foff(wc + ct * 16, fr, g4)];
#pragma unroll
            for (int rt = 0; rt < 4; ++rt)
#pragma unroll
                for (int ct = 0; ct < 4; ++ct) {
                    acc[rt][ct] = __builtin_amdgcn_mfma_f32_16x16x32_f16(
                        fa[rt], fb[ct], acc[rt][ct], 0, 0, 0);
                    acc[rt][ct] = __builtin_amdgcn_mfma_f32_16x16x32_f16(
                        fal[rt], fb[ct], acc[rt][ct], 0, 0, 0);
                }
            __syncthreads();
        }

        // accumulate exp(s + bet[n] - rho[m]) into per-col register sums
#pragma unroll
        for (int rt = 0; rt < 4; ++rt)
#pragma unroll
            for (int reg = 0; reg < 4; ++reg) {
                const float r = rho_s[wr + rt * 16 + g4 * 4 + reg];
#pragma unroll
                for (int ct = 0; ct < 4; ++ct)
                    csum[ct] += __expf(acc[rt][ct][reg] + bet_s[wc + ct * 16 + fr] - r);
            }
        __syncthreads();   // protect rho_s before next chunk's store
    }

    // reduce over the 4 row-lane groups, then across the row-wave pair
#pragma unroll
    for (int ct = 0; ct < 4; ++ct) {
        csum[ct] += __shfl_xor(csum[ct], 16);
        csum[ct] += __shfl_xor(csum[ct], 32);
    }
    if (lane < 16)
#pragma unroll
        for (int ct = 0; ct < 4; ++ct) cred[w][ct * 16 + lane] = csum[ct];
    __syncthreads();
    if (t < 128) {
        const int c = t & 63;
        const float s = (t < 64) ? (cred[0][c] + cred[2][c])
                                 : (cred[1][c] + cred[3][c]);
        pc[(size_t)sp * MM + bbase + n0 + t] = s;
    }
}

// ---------------------------------------------------------------------------
// colsc[n] = c/(eps+c), c = sum over splits of pc
// ---------------------------------------------------------------------------
__global__ __launch_bounds__(256)
void colsc_merge(const float* __restrict__ pc, float* __restrict__ colsc)
{
    const size_t i = (size_t)blockIdx.x * 256 + threadIdx.x;
    float c = 0.0f;
#pragma unroll
    for (int s = 0; s < NSPLIT; ++s) c += pc[s * (size_t)MM + i];
    colsc[i] = c / (1e-9f + c);
}

// ---------------------------------------------------------------------------
// Workspace (128 MiB): xh|xl|ah|al (4 x M*C f16). th aliases al; Wvt/Wot
// go into ah (dead after passB). Small scratch in d_out (dead before the
// final out-GEMM writes it).
// ---------------------------------------------------------------------------
extern "C" void kernel_launch(void* const* d_in, const int* in_sizes, int n_in,
                              void* d_out, int out_size, void* d_ws, size_t ws_size,
                              hipStream_t stream)
{
    const float* x        = (const float*)d_in[0];
    const float* Wq       = (const float*)d_in[1];
    const float* bq       = (const float*)d_in[2];
    const float* Wk       = (const float*)d_in[3];
    const float* bk       = (const float*)d_in[4];   (void)bk;  // softmax-invariant
    const float* Wv       = (const float*)d_in[5];
    const float* bv       = (const float*)d_in[6];
    const float* Wo       = (const float*)d_in[7];
    const float* bo       = (const float*)d_in[8];
    const float* bn_scale = (const float*)d_in[9];
    const float* bn_bias  = (const float*)d_in[10];
    const float* bn_mean  = (const float*)d_in[11];
    const float* bn_var   = (const float*)d_in[12];
    float* out = (float*)d_out;

    const size_t MMC = (size_t)MM * CC;   // 16,777,216
    _Float16* xh = (_Float16*)d_ws;
    _Float16* xl = xh + MMC;
    _Float16* ah = xl + MMC;
    _Float16* al = ah + MMC;
    _Float16* th  = al;                    // v-GEMM output aliases al
    _Float16* Wvt = ah;                    // converted after passB (ah dead)
    _Float16* Wot = ah + 512 * 512;

    // small scratch in d_out (all consumed before the final GEMM writes out)
    char* ob = (char*)d_out;
    _Float16* Pth = (_Float16*)(ob);                        //  512 KiB
    _Float16* Ptl = (_Float16*)(ob + (1u << 19));           //  512 KiB
    float* w2     = (float*)(ob + (2u << 19));              //    2 KiB
    float* bet    = (float*)(ob + (2u << 19) + 8192);       //  128 KiB
    float* rho    = (float*)(ob + 1318912);                 //  128 KiB
    float* colsc  = (float*)(ob + 1449984);                 //  128 KiB
    float* pm     = (float*)(ob + 1581056);                 //  512 KiB
    float* pl     = (float*)(ob + 2105344);                 //  512 KiB
    float* pc     = (float*)(ob + 2629632);                 //  512 KiB

    const dim3 blk(256);
    const dim3 g16(MM / 128, CC / 128);        // 256 x 4
    const dim3 gattn(NN / 128, BB, NSPLIT);    // 16 x 16 x 4

    split_x<<<MMC / (256 * 4), blk, 0, stream>>>(x, xh, xl);
    gemm_nt_split<<<dim3(8, 8), blk, 0, stream>>>(Wk, Wq, Pth, Ptl);
    calc_w2<<<2, blk, 0, stream>>>(Wk, bq, w2);
    calc_beta<<<MM / 4, blk, 0, stream>>>(x, w2, bet);

    // a = x @ (Wq Wk^T), split-stored (3-term)
    gemm16<true, 0><<<g16, blk, 0, stream>>>(xh, xl, Pth, Ptl,
        nullptr, nullptr, nullptr, nullptr, nullptr, nullptr, nullptr,
        ah, al, nullptr);

    attn_rowstats<<<gattn, blk, 0, stream>>>(ah, al, xh, bet, pm, pl);
    rho_merge<<<MM / 256, blk, 0, stream>>>(pm, pl, rho);
    attn_colsum<<<gattn, blk, 0, stream>>>(ah, al, xh, bet, rho, pc);
    colsc_merge<<<MM / 256, blk, 0, stream>>>(pc, colsc);

    // th = f16(colsc[row] * (x @ Wv + bv))
    conv_wT<<<1024, blk, 0, stream>>>(Wv, Wvt);
    gemm16<false, 1><<<g16, blk, 0, stream>>>(xh, nullptr, Wvt, nullptr,
        bv, colsc, nullptr, nullptr, nullptr, nullptr, nullptr,
        th, nullptr, nullptr);

    // out = relu(BN(th @ Wo + bo)) + x
    conv_wT<<<1024, blk, 0, stream>>>(Wo, Wot);
    gemm16<false, 2><<<g16, blk, 0, stream>>>(th, nullptr, Wot, nullptr,
        bo, nullptr, bn_scale, bn_bias, bn_mean, bn_var, x,
        nullptr, nullptr, out);
}